// Round 1
// baseline (656.182 us; speedup 1.0000x reference)
//
#include <hip/hip_runtime.h>
#include <math.h>

#define BB 192
#define DD 2048
#define HH 128

// D * log(2*pi) computed in f64 then rounded to f32 (matches JAX weak-type promotion)
#define D_LOG2PI 3763.9722320063395f

typedef float f32x4 __attribute__((ext_vector_type(4)));

// ---------------------------------------------------------------------------
// Kernel 1: fused 3-layer MLP head per (row, head). head 0 = mu, head 1 = lv.
// Writes mu[B*D], scale[B*D], inv_var[B*D], logdet[B] (= 0.5*sum(lv)) to ws.
// ---------------------------------------------------------------------------
__global__ __launch_bounds__(256) void head_kernel(
    const float* __restrict__ q,
    const float* __restrict__ mw1, const float* __restrict__ mb1,
    const float* __restrict__ mw2, const float* __restrict__ mb2,
    const float* __restrict__ mw3, const float* __restrict__ mb3,
    const float* __restrict__ lw1, const float* __restrict__ lb1,
    const float* __restrict__ lw2, const float* __restrict__ lb2,
    const float* __restrict__ lw3, const float* __restrict__ lb3,
    float* __restrict__ mu_out, float* __restrict__ scale_out,
    float* __restrict__ invvar_out, float* __restrict__ logdet_out)
{
    const int row  = blockIdx.x;
    const int head = blockIdx.y;   // 0 = mu, 1 = logvar
    const float* W1 = head ? lw1 : mw1;
    const float* B1 = head ? lb1 : mb1;
    const float* W2 = head ? lw2 : mw2;
    const float* B2 = head ? lb2 : mb2;
    const float* W3 = head ? lw3 : mw3;
    const float* B3 = head ? lb3 : mb3;

    __shared__ float qrow[DD];
    __shared__ float h1[HH];
    __shared__ float h2[HH];
    __shared__ float red[4];

    const int t = threadIdx.x;

    // stage q row into LDS (coalesced float4)
    {
        const f32x4* src = (const f32x4*)(q + (size_t)row * DD);
        f32x4* dst = (f32x4*)qrow;
        for (int i = t; i < DD / 4; i += 256) dst[i] = src[i];
    }
    __syncthreads();

    // ---- layer 1: D -> H, two threads per output (split-K) ----
    {
        const int o = t >> 1, half = t & 1;
        const f32x4* w4 = (const f32x4*)(W1 + (size_t)o * DD + half * (DD / 2));
        const f32x4* x4 = (const f32x4*)(qrow + half * (DD / 2));
        float acc = 0.f;
        #pragma unroll 4
        for (int k = 0; k < DD / 8; ++k) {
            f32x4 w = w4[k], x = x4[k];
            acc += w.x * x.x + w.y * x.y + w.z * x.z + w.w * x.w;
        }
        acc += __shfl_xor(acc, 1);
        if (half == 0) h1[o] = fmaxf(acc + B1[o], 0.f);
    }
    __syncthreads();

    // ---- layer 2: H -> H ----
    {
        const int o = t >> 1, half = t & 1;
        const f32x4* w4 = (const f32x4*)(W2 + o * HH + half * (HH / 2));
        const f32x4* x4 = (const f32x4*)(h1 + half * (HH / 2));
        float acc = 0.f;
        #pragma unroll
        for (int k = 0; k < HH / 8; ++k) {
            f32x4 w = w4[k], x = x4[k];
            acc += w.x * x.x + w.y * x.y + w.z * x.z + w.w * x.w;
        }
        acc += __shfl_xor(acc, 1);
        if (half == 0) h2[o] = fmaxf(acc + B2[o], 0.f);
    }
    __syncthreads();

    // ---- layer 3: H -> D, 8 outputs per thread ----
    float sumlv = 0.f;
    for (int m = 0; m < DD / 256; ++m) {
        const int j = m * 256 + t;
        const f32x4* w4 = (const f32x4*)(W3 + (size_t)j * HH);
        const f32x4* x4 = (const f32x4*)h2;
        float acc = 0.f;
        #pragma unroll
        for (int k = 0; k < HH / 4; ++k) {
            f32x4 w = w4[k], x = x4[k];
            acc += w.x * x.x + w.y * x.y + w.z * x.z + w.w * x.w;
        }
        float val = fmaxf(acc + B3[j], 0.f);
        if (head == 0) {
            mu_out[(size_t)row * DD + j] = val;
        } else {
            float var = expf(0.5f * val);   // covariance diagonal (matches reference)
            float sc  = sqrtf(var);         // per-dim scale = exp(0.25*lv)
            scale_out [(size_t)row * DD + j] = sc;
            invvar_out[(size_t)row * DD + j] = 1.0f / var;
            sumlv += val;
        }
    }
    if (head == 1) {
        #pragma unroll
        for (int off = 32; off; off >>= 1) sumlv += __shfl_down(sumlv, off);
        const int wid = t >> 6, lane = t & 63;
        if (lane == 0) red[wid] = sumlv;
        __syncthreads();
        if (t == 0) logdet_out[row] = 0.5f * (red[0] + red[1] + red[2] + red[3]);
    }
}

// ---------------------------------------------------------------------------
// Kernel 2: streaming p = mu + eps*scale, maha row-reduce, log_prob.
// One block per (i, j); blockIdx.x = i (fastest) so consecutive blocks share
// the same j-row of mu/scale/inv_var in L2.
// ---------------------------------------------------------------------------
__global__ __launch_bounds__(256) void sample_logprob_kernel(
    const float* __restrict__ eps,
    const float* __restrict__ mu, const float* __restrict__ scale,
    const float* __restrict__ invvar, const float* __restrict__ logdet,
    float* __restrict__ p_out, float* __restrict__ lp_out)
{
    const int i = blockIdx.x;
    const int j = blockIdx.y;
    const int t = threadIdx.x;

    const size_t base = ((size_t)(i * BB + j)) * DD;
    const f32x4* e4  = (const f32x4*)(eps + base);
    const f32x4* m4  = (const f32x4*)(mu + (size_t)j * DD);
    const f32x4* s4  = (const f32x4*)(scale + (size_t)j * DD);
    const f32x4* iv4 = (const f32x4*)(invvar + (size_t)j * DD);
    f32x4* p4 = (f32x4*)(p_out + base);

    float acc = 0.f;
    #pragma unroll
    for (int it = 0; it < DD / 1024; ++it) {
        const int idx = it * 256 + t;
        f32x4 e  = __builtin_nontemporal_load(&e4[idx]);   // streamed, no reuse
        f32x4 m  = m4[idx];                                // L2-hot per-j rows
        f32x4 s  = s4[idx];
        f32x4 iv = iv4[idx];
        f32x4 pv;
        pv.x = m.x + e.x * s.x;
        pv.y = m.y + e.y * s.y;
        pv.z = m.z + e.z * s.z;
        pv.w = m.w + e.w * s.w;
        float dx = pv.x - m.x, dy = pv.y - m.y, dz = pv.z - m.z, dw = pv.w - m.w;
        acc += dx * dx * iv.x;
        acc += dy * dy * iv.y;
        acc += dz * dz * iv.z;
        acc += dw * dw * iv.w;
        __builtin_nontemporal_store(pv, &p4[idx]);         // streamed, no reuse
    }

    // block reduce maha
    #pragma unroll
    for (int off = 32; off; off >>= 1) acc += __shfl_down(acc, off);
    __shared__ float red[4];
    const int wid = t >> 6, lane = t & 63;
    if (lane == 0) red[wid] = acc;
    __syncthreads();
    if (t == 0) {
        const float maha = red[0] + red[1] + red[2] + red[3];
        lp_out[(size_t)i * BB + j] = -0.5f * (maha + D_LOG2PI) - 0.5f * logdet[j];
    }
}

extern "C" void kernel_launch(void* const* d_in, const int* in_sizes, int n_in,
                              void* d_out, int out_size, void* d_ws, size_t ws_size,
                              hipStream_t stream) {
    (void)in_sizes; (void)n_in; (void)out_size; (void)ws_size;
    const float* q    = (const float*)d_in[0];
    const float* eps  = (const float*)d_in[1];
    const float* mw1  = (const float*)d_in[2];
    const float* mb1  = (const float*)d_in[3];
    const float* mw2  = (const float*)d_in[4];
    const float* mb2  = (const float*)d_in[5];
    const float* mw3  = (const float*)d_in[6];
    const float* mb3  = (const float*)d_in[7];
    const float* lw1  = (const float*)d_in[8];
    const float* lb1  = (const float*)d_in[9];
    const float* lw2  = (const float*)d_in[10];
    const float* lb2  = (const float*)d_in[11];
    const float* lw3  = (const float*)d_in[12];
    const float* lb3  = (const float*)d_in[13];

    float* ws      = (float*)d_ws;
    float* mu      = ws;                     // B*D
    float* scale   = ws + (size_t)BB * DD;   // B*D
    float* invvar  = ws + 2 * (size_t)BB * DD; // B*D
    float* logdet  = ws + 3 * (size_t)BB * DD; // B

    float* p  = (float*)d_out;                      // B*B*D
    float* lp = p + (size_t)BB * BB * DD;           // B*B

    head_kernel<<<dim3(BB, 2), 256, 0, stream>>>(
        q, mw1, mb1, mw2, mb2, mw3, mb3, lw1, lb1, lw2, lb2, lw3, lb3,
        mu, scale, invvar, logdet);

    sample_logprob_kernel<<<dim3(BB, BB), 256, 0, stream>>>(
        eps, mu, scale, invvar, logdet, p, lp);
}